// Round 21
// baseline (746.729 us; speedup 1.0000x reference)
//
#include <hip/hip_runtime.h>

// Problem constants (match reference setup_inputs)
#define D 64
constexpr int Pn  = 100000;
constexpr int Un  = 20000;
constexpr int Rn  = 1000;
constexpr int Cn  = 500;
constexpr int Tn  = 50;
constexpr int Bn  = 4096;
constexpr int ETn = 50000;
constexpr int NNZ_COL = 1000000;
constexpr int NNZ_REG = 300000;
constexpr int NNZ_CAT = 300000;
constexpr int NNZ_T   = 1000000;
constexpr int STILE = 7040;  // elements per scatter tile (55KB staging)
constexpr int NBMAX = 1024;  // max buckets per (graph,dir): reg dir1 = 1000
constexpr int CAP2 = 1536;   // poi-side bucket capacity (mean<=1279, sigma~36)
constexpr int NB2  = (Pn + 127) / 128;  // 782 poi buckets (shift 7)

static inline int cdiv(int a, int b) { return (a + b - 1) / b; }

__device__ __forceinline__ unsigned short f2bf(float f) {
  unsigned u = __float_as_uint(f);
  unsigned r = (u + 0x7FFF + ((u >> 16) & 1)) >> 16;  // round-to-nearest-even
  return (unsigned short)r;
}
__device__ __forceinline__ float bflo(unsigned d) {
  return __uint_as_float(d << 16);
}
__device__ __forceinline__ float bfhi(unsigned d) {
  return __uint_as_float(d & 0xFFFF0000u);
}
__device__ __forceinline__ unsigned packbf(float a, float b) {
  return (unsigned)f2bf(a) | ((unsigned)f2bf(b) << 16);
}

// Per-graph sort descriptor (batched sort kernels select by blockIdx).
struct SG {
  const int* k1; const int* o1; const float* v1;
  const int* k2; const int* o2; const float* v2;
  int2* sd; int* rowptr; int* cursorB;
  int s1, nb1, nk1, cap1, nblk, nnz, tile0, bkt0;
};
struct SG4 { SG g[4]; };

// Fused-gate descriptor (4 gates over the same input; p16 only).
struct G4 {
  const float* W[4]; const float* b[4];
  unsigned short* P[4];
};

// Batched 64x64 weight-product descriptor (6 products).
struct W6 { const float* A[6]; const float* Bm[6]; float* O[6]; };

// ---------------------------------------------------------------------------
// gate4: o_g = x * sigmoid(x @ W_g + b_g) for g=0..3, one read of X.
// Wave w owns gate w; 4 rows staged in LDS per iteration. Inner product
// reads the LDS row as float4 (ds_read_b128 broadcast) -> 80 issue-ops/row
// instead of 128.
// ---------------------------------------------------------------------------
__global__ __launch_bounds__(256) void gate4_kernel(G4 g,
                                                   const float* __restrict__ X,
                                                   int N) {
  __shared__ float sx[4][D];
  int tid = threadIdx.x, wv = tid >> 6, lane = tid & 63;
  float wcol[D];
  const float* Wg = g.W[wv];
#pragma unroll
  for (int k = 0; k < D; ++k) wcol[k] = Wg[k * D + lane];
  float bl = g.b[wv][lane];
  unsigned short* Pw = g.P[wv];
  for (int row0 = blockIdx.x * 4; row0 < N; row0 += gridDim.x * 4) {
    sx[wv][lane] = X[(size_t)(row0 + wv) * D + lane];
    __syncthreads();
#pragma unroll
    for (int r = 0; r < 4; ++r) {
      const float4* sx4 = (const float4*)sx[r];
      float y = 0.f;
#pragma unroll
      for (int k4 = 0; k4 < 16; ++k4) {
        float4 xv = sx4[k4];
        y += xv.x * wcol[4 * k4] + xv.y * wcol[4 * k4 + 1] +
             xv.z * wcol[4 * k4 + 2] + xv.w * wcol[4 * k4 + 3];
      }
      float x = sx[r][lane];
      float s = 1.f / (1.f + __expf(-(y + bl)));
      Pw[(size_t)(row0 + r) * D + lane] = f2bf(x * s);
    }
    __syncthreads();
  }
}

// Batched 64x64 weight products: O[p] = A[p] @ Bm[p]; 16 blocks/product.
__global__ __launch_bounds__(256) void wprod_kernel(W6 w) {
  __shared__ float sx[4][D];
  int tid = threadIdx.x, wv = tid >> 6, lane = tid & 63;
  int p = blockIdx.x >> 4, blk = blockIdx.x & 15;
  const float* A = w.A[p];
  const float* Bm = w.Bm[p];
  float* O = w.O[p];
  float wcol[D];
#pragma unroll
  for (int k = 0; k < D; ++k) wcol[k] = Bm[k * D + lane];
  int row = blk * 4 + wv;
  sx[wv][lane] = A[row * D + lane];
  float y = 0.f;
#pragma unroll
  for (int k = 0; k < D; ++k) y += sx[wv][k] * wcol[k];
  O[row * D + lane] = y;
}

// fused hetero edge update + residual (weights pre-folded):
// fused = msg' @ WpWf + e_buf @ WeWf ; fusedOut16 = bf16(fused);
// e_buf += fused ; accE += e_buf(new). LDS rows read as float4.
__global__ __launch_bounds__(256) void fused2_resid_kernel(
    const float* __restrict__ A, const float* __restrict__ W1,
    const float* __restrict__ W2, unsigned short* __restrict__ fusedOut16,
    float* __restrict__ e_buf, float* __restrict__ accE, int N) {
  __shared__ float sa[4][D], sb2[4][D];
  int tid = threadIdx.x, wv = tid >> 6, lane = tid & 63;
  float w1[D], w2[D];
#pragma unroll
  for (int k = 0; k < D; ++k) {
    w1[k] = W1[k * D + lane];
    w2[k] = W2[k * D + lane];
  }
  for (int row = blockIdx.x * 4 + wv; row < N; row += gridDim.x * 4) {
    sa[wv][lane]  = A[row * D + lane];
    float eo = e_buf[row * D + lane];
    sb2[wv][lane] = eo;
    const float4* a4 = (const float4*)sa[wv];
    const float4* b4 = (const float4*)sb2[wv];
    float y = 0.f;
#pragma unroll
    for (int k4 = 0; k4 < 16; ++k4) {
      float4 av = a4[k4];
      float4 bv = b4[k4];
      y += av.x * w1[4 * k4] + av.y * w1[4 * k4 + 1] +
           av.z * w1[4 * k4 + 2] + av.w * w1[4 * k4 + 3];
      y += bv.x * w2[4 * k4] + bv.y * w2[4 * k4 + 1] +
           bv.z * w2[4 * k4 + 2] + bv.w * w2[4 * k4 + 3];
    }
    fusedOut16[row * D + lane] = f2bf(y);
    float en = eo + y;
    e_buf[row * D + lane] = en;
    accE[row * D + lane] += en;
  }
}

// Batched cursor init: cursorB[local b] = fixed bucket base.
__global__ __launch_bounds__(256) void cursor_init_b_kernel(SG4 gs, int totb) {
  int b = blockIdx.x * blockDim.x + threadIdx.x;
  if (b >= totb) return;
  int gi = 3;
  while (gi > 0 && b < gs.g[gi].bkt0) --gi;
  const SG& g = gs.g[gi];
  int lb = b - g.bkt0;
  g.cursorB[lb] =
      (lb < g.nb1) ? lb * g.cap1 : g.nb1 * g.cap1 + (lb - g.nb1) * CAP2;
}

// ---------------------------------------------------------------------------
// Batched LDS-STAGED scatter: per (graph,dir,tile) block, bucket-sort the
// tile in LDS, then emit each bucket's run as a coalesced burst (full-line
// writes, no RMW churn). lcnt aliases stage (dead before staging written).
// LDS: stage 2*STILE ints | lbase NBMAX+1 | gbase NBMAX  (64516B <= 64KB)
// ---------------------------------------------------------------------------
__global__ __launch_bounds__(1024) void scatter_b_kernel(SG4 gs) {
  extern __shared__ int ls[];
  int2* stage = (int2*)ls;             // STILE int2 = 55KB
  int* lcnt   = ls;                    // aliases stage (first nb ints)
  int* lbase  = ls + 2 * STILE;        // NBMAX+1
  int* gbase  = lbase + (NBMAX + 1);   // NBMAX
  __shared__ int wsum[17];
  int b = blockIdx.x;
  int gi = 3;
  while (gi > 0 && b < gs.g[gi].tile0) --gi;
  const SG& g = gs.g[gi];
  int t = b - g.tile0;
  bool d2 = t >= g.nblk;
  const int* kk = d2 ? g.k2 : g.k1;
  const int* oo = d2 ? g.o2 : g.o1;
  const float* vv = d2 ? g.v2 : g.v1;
  int sft = d2 ? 7 : g.s1;
  int kb = d2 ? g.nb1 : 0;
  int nb = d2 ? NB2 : g.nb1;
  int msk = (1 << sft) - 1;
  int tile = d2 ? t - g.nblk : t;
  int tid = threadIdx.x;
  for (int k = tid; k < nb; k += 1024) lcnt[k] = 0;
  __syncthreads();
  int t0 = tile * STILE, t1 = min(t0 + STILE, g.nnz);
  int fill = t1 - t0;
  int key[7], off[7], ox[7], vx[7];
#pragma unroll
  for (int j = 0; j < 7; ++j) {
    int i = t0 + j * 1024 + tid;
    if (i < t1) {
      int r = kk[i];
      key[j] = r >> sft;
      ox[j] = ((r & msk) << 17) | oo[i];
      vx[j] = __float_as_int(vv[i]);
      off[j] = atomicAdd(&lcnt[key[j]], 1);
    } else {
      key[j] = -1; off[j] = 0; ox[j] = 0; vx[j] = 0;
    }
  }
  __syncthreads();
  // exclusive scan of lcnt[0..nb) -> lbase; reserve global space -> gbase
  {
    int lane = tid & 63, wv = tid >> 6;
    int c = (tid < nb) ? lcnt[tid] : 0;
    int sc = c;
#pragma unroll
    for (int d = 1; d < 64; d <<= 1) {
      int y = __shfl_up(sc, d);
      if (lane >= d) sc += y;
    }
    if (lane == 63) wsum[wv] = sc;
    __syncthreads();
    if (tid < 16) {
      int w = wsum[tid];
#pragma unroll
      for (int d = 1; d < 16; d <<= 1) {
        int y = __shfl_up(w, d);
        if (lane >= d) w += y;
      }
      wsum[tid] = w;
    }
    __syncthreads();
    int woff = (wv == 0) ? 0 : wsum[wv - 1];
    if (tid < nb) {
      lbase[tid] = woff + sc - c;
      gbase[tid] = c ? atomicAdd(&g.cursorB[kb + tid], c) : 0;
    }
    if (tid == 0) lbase[nb] = fill;
  }
  __syncthreads();  // lcnt dead; staging (aliased) may now be written
#pragma unroll
  for (int j = 0; j < 7; ++j)
    if (key[j] >= 0) stage[lbase[key[j]] + off[j]] = make_int2(ox[j], vx[j]);
  __syncthreads();
  // out-copy: consecutive i -> consecutive dst within runs (coalesced)
  for (int i = tid; i < fill; i += 1024) {
    int lo = 0, hi = nb;
    while (hi - lo > 1) {
      int mid = (lo + hi) >> 1;
      if (lbase[mid] <= i) lo = mid; else hi = mid;
    }
    g.sd[gbase[lo] + (i - lbase[lo])] = stage[i];
  }
}

// Batched refine: bucket-grouped -> exact row-grouped IN PLACE + exact
// rowptr. Block per bucket; <=2048 elems staged in registers. rows==1:
// just write rowptr.
__global__ __launch_bounds__(256) void refine_b_kernel(SG4 gs) {
  __shared__ int cnt[128];
  __shared__ int wsum[2];
  int bg = blockIdx.x;
  int gi = 3;
  while (gi > 0 && bg < gs.g[gi].bkt0) --gi;
  const SG& g = gs.g[gi];
  int b = bg - g.bkt0;
  int tid = threadIdx.x;
  int sft, row0, kbase, klim, bstart;
  if (b < g.nb1) {
    sft = g.s1; row0 = b << g.s1; kbase = 0; klim = g.nk1;
    bstart = b * g.cap1;
  } else {
    sft = 7; row0 = (b - g.nb1) << 7; kbase = g.nk1; klim = Pn;
    bstart = g.nb1 * g.cap1 + (b - g.nb1) * CAP2;
  }
  int rows = min(1 << sft, klim - row0);
  int bend = g.cursorB[b];
  if (rows == 1) {
    if (tid == 0) g.rowptr[kbase + row0] = bstart;
    return;
  }
  if (tid < rows) cnt[tid] = 0;
  __syncthreads();
  int2 st[8];
#pragma unroll
  for (int j = 0; j < 8; ++j) {
    int i = bstart + tid + (j << 8);
    st[j] = (i < bend) ? g.sd[i] : make_int2(0, 0);
  }
#pragma unroll
  for (int j = 0; j < 8; ++j) {
    int i = bstart + tid + (j << 8);
    if (i < bend) atomicAdd(&cnt[st[j].x >> 17], 1);
  }
  __syncthreads();
  int v = 0, sc = 0;
  if (tid < 128) {
    v = (tid < rows) ? cnt[tid] : 0;
    sc = v;
    int lane = tid & 63;
#pragma unroll
    for (int d = 1; d < 64; d <<= 1) {
      int y = __shfl_up(sc, d);
      if (lane >= d) sc += y;
    }
    if (lane == 63) wsum[tid >> 6] = sc;
  }
  __syncthreads();
  int excl = sc - v + ((tid >= 64 && tid < 128) ? wsum[0] : 0);
  __syncthreads();  // cnt reads done before overwrite
  if (tid < rows) {
    g.rowptr[kbase + row0 + tid] = bstart + excl;
    cnt[tid] = excl;  // becomes placement cursor
  }
  __syncthreads();
#pragma unroll
  for (int j = 0; j < 8; ++j) {
    int i = bstart + tid + (j << 8);
    if (i < bend) {
      int r = st[j].x >> 17;
      int dst = bstart + atomicAdd(&cnt[r], 1);
      g.sd[dst] = st[j];
    }
  }
}

// ---------------------------------------------------------------------------
// Exact-CSR SpMM: wave per row, 8 nnz per gather instruction (8 lanes x
// uint4 = 128B bf16 row per nnz). Row end = min(rowptr[idx+1], bucket end).
// Merge via shfl ^8,^16,^32; lanes 0-7 do the epilogue. Modes: Yf (f32 out),
// Y128 (bf16 out), or C-mode bf16 p RMW (p128 += y) with acc modes:
// amode 1: a128 = p_old + p_new (pure store; layer-1 acc init+update),
// amode 2: a128 += p_new (layer-2 acc update).
// ---------------------------------------------------------------------------
__global__ __launch_bounds__(256) void spmm_csr_kernel(
    const int* __restrict__ rowptr, const int* __restrict__ bEnd, int base,
    int nkx, int sft, int boff, const int2* __restrict__ sd,
    const uint4* __restrict__ X128, float* __restrict__ Yf,
    uint4* __restrict__ Y128, uint4* __restrict__ p128,
    uint4* __restrict__ a128, int amode, int nrows) {
  int lane = threadIdx.x & 63;
  int q = lane >> 3, l3 = lane & 7;  // octet q (0..7), lane-in-octet
  int w = (int)((blockIdx.x * (long)blockDim.x + threadIdx.x) >> 6);
  if (w >= nrows) return;
  int idx = base + w;
  int start = rowptr[idx];
  int be = bEnd[boff + (w >> sft)];
  int end = (idx + 1 < nkx) ? min(rowptr[idx + 1], be) : be;
  float a0 = 0.f, a1 = 0.f, a2 = 0.f, a3 = 0.f;
  float a4 = 0.f, a5 = 0.f, a6 = 0.f, a7 = 0.f;
  float b0 = 0.f, b1 = 0.f, b2 = 0.f, b3 = 0.f;
  float b4 = 0.f, b5 = 0.f, b6 = 0.f, b7 = 0.f;
  int n = start + q;  // this octet's nnz stream (stride 8)
  for (; n + 8 < end; n += 16) {
    int2 c0 = sd[n], c1 = sd[n + 8];
    uint4 d0 = X128[(size_t)(c0.x & 0x1FFFF) * 8 + l3];
    uint4 d1 = X128[(size_t)(c1.x & 0x1FFFF) * 8 + l3];
    float v0 = __int_as_float(c0.y), v1 = __int_as_float(c1.y);
    a0 += v0 * bflo(d0.x); a1 += v0 * bfhi(d0.x);
    a2 += v0 * bflo(d0.y); a3 += v0 * bfhi(d0.y);
    a4 += v0 * bflo(d0.z); a5 += v0 * bfhi(d0.z);
    a6 += v0 * bflo(d0.w); a7 += v0 * bfhi(d0.w);
    b0 += v1 * bflo(d1.x); b1 += v1 * bfhi(d1.x);
    b2 += v1 * bflo(d1.y); b3 += v1 * bfhi(d1.y);
    b4 += v1 * bflo(d1.z); b5 += v1 * bfhi(d1.z);
    b6 += v1 * bflo(d1.w); b7 += v1 * bfhi(d1.w);
  }
  for (; n < end; n += 8) {
    int2 cv = sd[n];
    uint4 dv = X128[(size_t)(cv.x & 0x1FFFF) * 8 + l3];
    float v = __int_as_float(cv.y);
    a0 += v * bflo(dv.x); a1 += v * bfhi(dv.x);
    a2 += v * bflo(dv.y); a3 += v * bfhi(dv.y);
    a4 += v * bflo(dv.z); a5 += v * bfhi(dv.z);
    a6 += v * bflo(dv.w); a7 += v * bfhi(dv.w);
  }
  float y0 = a0 + b0, y1 = a1 + b1, y2 = a2 + b2, y3 = a3 + b3;
  float y4 = a4 + b4, y5 = a5 + b5, y6 = a6 + b6, y7 = a7 + b7;
#pragma unroll
  for (int m = 8; m <= 32; m <<= 1) {
    y0 += __shfl(y0, lane ^ m); y1 += __shfl(y1, lane ^ m);
    y2 += __shfl(y2, lane ^ m); y3 += __shfl(y3, lane ^ m);
    y4 += __shfl(y4, lane ^ m); y5 += __shfl(y5, lane ^ m);
    y6 += __shfl(y6, lane ^ m); y7 += __shfl(y7, lane ^ m);
  }
  if (lane >= 8) return;
  size_t o = (size_t)w * 8 + l3;  // uint4 index (8 bf16 elems)
  if (p128) {
    uint4 pv = p128[o];
    float q0 = bflo(pv.x), q1 = bfhi(pv.x);
    float q2 = bflo(pv.y), q3 = bfhi(pv.y);
    float q4 = bflo(pv.z), q5 = bfhi(pv.z);
    float q6 = bflo(pv.w), q7 = bfhi(pv.w);
    float p0 = q0 + y0, p1 = q1 + y1, p2 = q2 + y2, p3 = q3 + y3;
    float p4 = q4 + y4, p5 = q5 + y5, p6 = q6 + y6, p7 = q7 + y7;
    uint4 pn;
    pn.x = packbf(p0, p1); pn.y = packbf(p2, p3);
    pn.z = packbf(p4, p5); pn.w = packbf(p6, p7);
    p128[o] = pn;
    if (amode == 1) {  // acc = p_old + p_new (pure store)
      uint4 an;
      an.x = packbf(q0 + p0, q1 + p1);
      an.y = packbf(q2 + p2, q3 + p3);
      an.z = packbf(q4 + p4, q5 + p5);
      an.w = packbf(q6 + p6, q7 + p7);
      a128[o] = an;
    } else if (amode == 2) {  // acc += p_new
      uint4 av = a128[o];
      uint4 an;
      an.x = packbf(bflo(av.x) + p0, bfhi(av.x) + p1);
      an.y = packbf(bflo(av.y) + p2, bfhi(av.y) + p3);
      an.z = packbf(bflo(av.z) + p4, bfhi(av.z) + p5);
      an.w = packbf(bflo(av.w) + p6, bfhi(av.w) + p7);
      a128[o] = an;
    }
  } else if (Y128) {
    uint4 pk;
    pk.x = packbf(y0, y1); pk.y = packbf(y2, y3);
    pk.z = packbf(y4, y5); pk.w = packbf(y6, y7);
    Y128[o] = pk;
  } else {
    float4 lo; lo.x = y0; lo.y = y1; lo.z = y2; lo.w = y3;
    float4 hi; hi.x = y4; hi.y = y5; hi.z = y6; hi.w = y7;
    *(float4*)&Yf[(size_t)w * D + 8 * l3] = lo;
    *(float4*)&Yf[(size_t)w * D + 8 * l3 + 4] = hi;
  }
}

// a = src; b = src  (float4)
__global__ __launch_bounds__(256) void copy2_kernel(
    const float4* __restrict__ s, float4* __restrict__ a,
    float4* __restrict__ b, int n4) {
  int i = blockIdx.x * blockDim.x + threadIdx.x;
  if (i < n4) {
    float4 v = s[i];
    a[i] = v;
    b[i] = v;
  }
}

// ---------------------------------------------------------------------------
// Final pooling over bf16 acc tables: wave per user, quarter q handles
// timesteps t=q,q+4,...; 16 lanes x uint2 = 128B row per gather. Merge via
// shfl ^16,^32; lanes 0-15 write float4 outputs. colU stays f32.
// ---------------------------------------------------------------------------
__global__ __launch_bounds__(256) void final_kernel(
    const int* __restrict__ user_idx, const int* __restrict__ seq,
    const int* __restrict__ mask, const uint2* __restrict__ colP16,
    const uint2* __restrict__ transP16, const uint2* __restrict__ regP16,
    const uint2* __restrict__ catP16, const float* __restrict__ colU,
    float* __restrict__ out) {
  int lane = threadIdx.x & 63;
  int q = lane >> 4, l4 = lane & 15;
  int wid = (int)((blockIdx.x * (long)blockDim.x + threadIdx.x) >> 6);
  if (wid >= Bn) return;
  float c0 = 0.f, c1 = 0.f, c2 = 0.f, c3 = 0.f;
  float t0 = 0.f, t1 = 0.f, t2 = 0.f, t3 = 0.f;
  float r0 = 0.f, r1 = 0.f, r2 = 0.f, r3 = 0.f;
  float g0 = 0.f, g1 = 0.f, g2 = 0.f, g3 = 0.f;
  int cnt = 0;
  for (int t = q; t < Tn; t += 4) {
    int m = mask[wid * Tn + t];
    int idx = seq[wid * Tn + t];
    cnt += m;
    if (m && idx < Pn) {
      size_t ro = (size_t)idx * 16 + l4;
      uint2 dc = colP16[ro];
      uint2 dt = transP16[ro];
      uint2 dr = regP16[ro];
      uint2 dg = catP16[ro];
      c0 += bflo(dc.x); c1 += bfhi(dc.x); c2 += bflo(dc.y); c3 += bfhi(dc.y);
      t0 += bflo(dt.x); t1 += bfhi(dt.x); t2 += bflo(dt.y); t3 += bfhi(dt.y);
      r0 += bflo(dr.x); r1 += bfhi(dr.x); r2 += bflo(dr.y); r3 += bfhi(dr.y);
      g0 += bflo(dg.x); g1 += bfhi(dg.x); g2 += bflo(dg.y); g3 += bfhi(dg.y);
    }
  }
  cnt += __shfl(cnt, lane ^ 16); cnt += __shfl(cnt, lane ^ 32);
  c0 += __shfl(c0, lane ^ 16); c0 += __shfl(c0, lane ^ 32);
  c1 += __shfl(c1, lane ^ 16); c1 += __shfl(c1, lane ^ 32);
  c2 += __shfl(c2, lane ^ 16); c2 += __shfl(c2, lane ^ 32);
  c3 += __shfl(c3, lane ^ 16); c3 += __shfl(c3, lane ^ 32);
  t0 += __shfl(t0, lane ^ 16); t0 += __shfl(t0, lane ^ 32);
  t1 += __shfl(t1, lane ^ 16); t1 += __shfl(t1, lane ^ 32);
  t2 += __shfl(t2, lane ^ 16); t2 += __shfl(t2, lane ^ 32);
  t3 += __shfl(t3, lane ^ 16); t3 += __shfl(t3, lane ^ 32);
  r0 += __shfl(r0, lane ^ 16); r0 += __shfl(r0, lane ^ 32);
  r1 += __shfl(r1, lane ^ 16); r1 += __shfl(r1, lane ^ 32);
  r2 += __shfl(r2, lane ^ 16); r2 += __shfl(r2, lane ^ 32);
  r3 += __shfl(r3, lane ^ 16); r3 += __shfl(r3, lane ^ 32);
  g0 += __shfl(g0, lane ^ 16); g0 += __shfl(g0, lane ^ 32);
  g1 += __shfl(g1, lane ^ 16); g1 += __shfl(g1, lane ^ 32);
  g2 += __shfl(g2, lane ^ 16); g2 += __shfl(g2, lane ^ 32);
  g3 += __shfl(g3, lane ^ 16); g3 += __shfl(g3, lane ^ 32);
  if (lane >= 16) return;
  float dn = 1.f / (float)(cnt > 0 ? cnt : 1);
  const float inv = 1.f / 3.f;  // 1/(N_LAYERS+1), common to all four nets
  int u = user_idx[wid];
  float4 cu = *(const float4*)&colU[(size_t)u * D + 4 * l4];
  size_t ob = (size_t)wid * D + 4 * l4;
  float4 o0;
  o0.x = (cu.x + c0 * dn) * inv; o0.y = (cu.y + c1 * dn) * inv;
  o0.z = (cu.z + c2 * dn) * inv; o0.w = (cu.w + c3 * dn) * inv;
  *(float4*)&out[0 * Bn * D + ob] = o0;
  float4 o1v;
  o1v.x = t0 * dn * inv; o1v.y = t1 * dn * inv;
  o1v.z = t2 * dn * inv; o1v.w = t3 * dn * inv;
  *(float4*)&out[1 * Bn * D + ob] = o1v;
  float4 o2v;
  o2v.x = r0 * dn * inv; o2v.y = r1 * dn * inv;
  o2v.z = r2 * dn * inv; o2v.w = r3 * dn * inv;
  *(float4*)&out[2 * Bn * D + ob] = o2v;
  float4 o3v;
  o3v.x = g0 * dn * inv; o3v.y = g1 * dn * inv;
  o3v.z = g2 * dn * inv; o3v.w = g3 * dn * inv;
  *(float4*)&out[3 * Bn * D + ob] = o3v;
}

extern "C" void kernel_launch(void* const* d_in, const int* in_sizes, int n_in,
                              void* d_out, int out_size, void* d_ws,
                              size_t ws_size, hipStream_t stream) {
  (void)in_sizes; (void)n_in; (void)out_size; (void)ws_size;
  const int*   user_idx      = (const int*)d_in[0];
  const int*   user_seq      = (const int*)d_in[1];
  const int*   user_seq_mask = (const int*)d_in[2];
  const int*   col_poi_idx   = (const int*)d_in[3];
  const int*   col_user_idx  = (const int*)d_in[4];
  const float* col_vals_pe   = (const float*)d_in[5];
  const float* col_vals_ep   = (const float*)d_in[6];
  const int*   reg_poi_idx   = (const int*)d_in[7];
  const int*   reg_region_idx= (const int*)d_in[8];
  const float* reg_vals_pe   = (const float*)d_in[9];
  const float* reg_vals_ep   = (const float*)d_in[10];
  const int*   cat_poi_idx   = (const int*)d_in[11];
  const int*   cat_cat_idx   = (const int*)d_in[12];
  const float* cat_vals_pe   = (const float*)d_in[13];
  const float* cat_vals_ep   = (const float*)d_in[14];
  const int*   trans_poi_idx = (const int*)d_in[15];
  const int*   trans_edge_idx= (const int*)d_in[16];
  const float* trans_vals_tar= (const float*)d_in[17];
  const float* trans_vals_src= (const float*)d_in[18];
  const float* poi_emb       = (const float*)d_in[19];
  const float* user_emb      = (const float*)d_in[20];
  const float* region_emb    = (const float*)d_in[21];
  const float* cat_emb       = (const float*)d_in[22];
  const float* w_gate_col    = (const float*)d_in[23];
  const float* b_gate_col    = (const float*)d_in[24];
  const float* w_gate_trans  = (const float*)d_in[25];
  const float* b_gate_trans  = (const float*)d_in[26];
  const float* w_gate_reg    = (const float*)d_in[27];
  const float* b_gate_reg    = (const float*)d_in[28];
  const float* w_gate_cat    = (const float*)d_in[29];
  const float* b_gate_cat    = (const float*)d_in[30];
  const float* col_Wp = (const float*)d_in[31];
  const float* col_We = (const float*)d_in[32];
  const float* col_Wf = (const float*)d_in[33];
  const float* reg_Wp = (const float*)d_in[34];
  const float* reg_We = (const float*)d_in[35];
  const float* reg_Wf = (const float*)d_in[36];
  const float* cat_Wp = (const float*)d_in[37];
  const float* cat_We = (const float*)d_in[38];
  const float* cat_Wf = (const float*)d_in[39];

  float* ws = (float*)d_ws;
  size_t off = 0;
  auto alloc = [&](size_t n) { float* p = ws + off; off += n; return p; };
  const size_t PD = (size_t)Pn * D;
  const size_t UD = (size_t)Un * D;
  const size_t ED = (size_t)ETn * D;

  float* colU   = alloc(UD);
  float* e_buf  = alloc(UD);
  float* tmpE1  = alloc(UD);
  float* acce   = alloc((size_t)Rn * D);
  float* Wbuf   = alloc(6 * D * D);  // WpWf/WeWf for the 3 hetero nets
  unsigned short* tmpE2_16 = (unsigned short*)alloc(UD / 2);
  unsigned short* tmpE1_16 = (unsigned short*)alloc(ED / 2);
  unsigned short* p16_0    = (unsigned short*)alloc(PD / 2);  // per-net p
  unsigned short* p16_1    = (unsigned short*)alloc(PD / 2);
  unsigned short* p16_2    = (unsigned short*)alloc(PD / 2);
  unsigned short* p16_3    = (unsigned short*)alloc(PD / 2);
  unsigned short* colP16   = (unsigned short*)alloc(PD / 2);  // bf16 acc tables
  unsigned short* regP16   = (unsigned short*)alloc(PD / 2);
  unsigned short* catP16   = (unsigned short*)alloc(PD / 2);
  unsigned short* transP16 = (unsigned short*)alloc(PD / 2);

  // Per-graph geometry (col, reg, cat, trans)
  const int s1_[4]   = {5, 0, 0, 6};
  const int nk1_[4]  = {Un, Rn, Cn, ETn};
  const int cap1_[4] = {2048, 512, 1024, 1536};
  const int nnz_[4]  = {NNZ_COL, NNZ_REG, NNZ_CAT, NNZ_T};
  SG4 gs;
  int tile0 = 0, bkt0 = 0;
  size_t sdoff = 0, rpoff = 0;
  int2* sdbase;
  int *rpbase, *curbase;
  {
    size_t sdtot = 0;
    for (int i = 0; i < 4; ++i) {
      int nb1 = cdiv(nk1_[i], 1 << s1_[i]);
      sdtot += (size_t)nb1 * cap1_[i] + (size_t)NB2 * CAP2;
    }
    sdbase = (int2*)alloc(2 * sdtot);
    rpbase = (int*)alloc(Un + Rn + Cn + ETn + 4 * Pn + 8);
    curbase = (int*)alloc(4 * 2048);
  }
  const int* k1s[4] = {col_user_idx, reg_region_idx, cat_cat_idx,
                       trans_edge_idx};
  const int* o1s[4] = {col_poi_idx, reg_poi_idx, cat_poi_idx, trans_poi_idx};
  const float* v1s[4] = {col_vals_pe, reg_vals_pe, cat_vals_pe,
                         trans_vals_tar};
  const float* v2s[4] = {col_vals_ep, reg_vals_ep, cat_vals_ep,
                         trans_vals_src};
  for (int i = 0; i < 4; ++i) {
    SG& g = gs.g[i];
    g.k1 = k1s[i]; g.o1 = o1s[i]; g.v1 = v1s[i];
    g.k2 = o1s[i]; g.o2 = k1s[i]; g.v2 = v2s[i];
    g.s1 = s1_[i]; g.nk1 = nk1_[i]; g.cap1 = cap1_[i]; g.nnz = nnz_[i];
    g.nb1 = cdiv(g.nk1, 1 << g.s1);
    g.nblk = cdiv(g.nnz, STILE);
    g.sd = sdbase + sdoff;
    g.rowptr = rpbase + rpoff;
    g.cursorB = curbase + i * 2048;
    g.tile0 = tile0; g.bkt0 = bkt0;
    sdoff += (size_t)g.nb1 * g.cap1 + (size_t)NB2 * CAP2;
    rpoff += g.nk1 + Pn;
    tile0 += 2 * g.nblk;
    bkt0 += g.nb1 + NB2;
  }
  int tottiles = tile0, totbkt = bkt0;

  // --- precompute all 6 weight products in one launch ---
  W6 w6;
  w6.A[0] = col_Wp; w6.Bm[0] = col_Wf;          w6.O[0] = Wbuf + 0 * D * D;
  w6.A[1] = col_We; w6.Bm[1] = col_Wf + D * D;  w6.O[1] = Wbuf + 1 * D * D;
  w6.A[2] = reg_Wp; w6.Bm[2] = reg_Wf;          w6.O[2] = Wbuf + 2 * D * D;
  w6.A[3] = reg_We; w6.Bm[3] = reg_Wf + D * D;  w6.O[3] = Wbuf + 3 * D * D;
  w6.A[4] = cat_Wp; w6.Bm[4] = cat_Wf;          w6.O[4] = Wbuf + 4 * D * D;
  w6.A[5] = cat_We; w6.Bm[5] = cat_Wf + D * D;  w6.O[5] = Wbuf + 5 * D * D;
  wprod_kernel<<<96, 256, 0, stream>>>(w6);

  // --- fused 4-gate pass (reads poi_emb once; p16 only) ---
  G4 g4;
  g4.W[0] = w_gate_col;   g4.b[0] = b_gate_col;   g4.P[0] = p16_0;
  g4.W[1] = w_gate_reg;   g4.b[1] = b_gate_reg;   g4.P[1] = p16_1;
  g4.W[2] = w_gate_cat;   g4.b[2] = b_gate_cat;   g4.P[2] = p16_2;
  g4.W[3] = w_gate_trans; g4.b[3] = b_gate_trans; g4.P[3] = p16_3;
  gate4_kernel<<<2048, 256, 0, stream>>>(g4, poi_emb, Pn);

  // --- batched sort phase (all four graphs) ---
  cursor_init_b_kernel<<<cdiv(totbkt, 256), 256, 0, stream>>>(gs, totbkt);
  scatter_b_kernel<<<tottiles, 1024, (2 * STILE + 2 * NBMAX + 1) * 4,
                     stream>>>(gs);
  refine_b_kernel<<<totbkt, 256, 0, stream>>>(gs);

  const int GCAP = 1024;

  auto spmm = [&](const SG& g, int base, int sft, int boff,
                  const unsigned short* X16, float* Yf, unsigned short* Y16,
                  unsigned short* prmw, unsigned short* armw, int amode,
                  int nrows) {
    spmm_csr_kernel<<<cdiv(nrows, 4), 256, 0, stream>>>(
        g.rowptr, g.cursorB, base, g.nk1 + Pn, sft, boff, g.sd,
        (const uint4*)X16, Yf, (uint4*)Y16, (uint4*)prmw, (uint4*)armw, amode,
        nrows);
  };

  auto hetero = [&](int gi, const float* edge_emb, int Ne, float* accE,
                    unsigned short* p16, unsigned short* acc16) {
    const SG& g = gs.g[gi];
    const float* WpWf = Wbuf + (2 * gi) * D * D;
    const float* WeWf = Wbuf + (2 * gi + 1) * D * D;
    copy2_kernel<<<cdiv(Ne * D / 4, 256), 256, 0, stream>>>(
        (const float4*)edge_emb, (float4*)e_buf, (float4*)accE, Ne * D / 4);
    for (int l = 0; l < 2; ++l) {
      // poi_msg' = A_pe @ p16  (Wp folded into WpWf downstream)
      spmm(g, 0, g.s1, 0, p16, tmpE1, nullptr, nullptr, nullptr, 0, Ne);
      fused2_resid_kernel<<<min(cdiv(Ne, 4), GCAP), 256, 0, stream>>>(
          tmpE1, WpWf, WeWf, tmpE2_16, e_buf, accE, Ne);
      // prop + bf16 p RMW; layer 1 stores acc = p_old + p_new (init+update),
      // layer 2 does acc += p_new.
      spmm(g, g.nk1, 7, g.nb1, tmpE2_16, nullptr, nullptr, p16, acc16,
           (l == 0) ? 1 : 2, Pn);
    }
  };

  hetero(0, user_emb, Un, colU, p16_0, colP16);
  hetero(1, region_emb, Rn, acce, p16_1, regP16);
  hetero(2, cat_emb, Cn, acce, p16_2, catP16);

  // --- directed trans net ---
  {
    const SG& g = gs.g[3];
    for (int l = 0; l < 2; ++l) {
      spmm(g, 0, g.s1, 0, p16_3, nullptr, tmpE1_16, nullptr, nullptr, 0, ETn);
      spmm(g, g.nk1, 7, g.nb1, tmpE1_16, nullptr, nullptr, p16_3, transP16,
           (l == 0) ? 1 : 2, Pn);
    }
  }

  // --- sequence pooling + output (bf16 acc tables) ---
  final_kernel<<<cdiv(Bn * 64, 256), 256, 0, stream>>>(
      user_idx, user_seq, user_seq_mask, (const uint2*)colP16,
      (const uint2*)transP16, (const uint2*)regP16, (const uint2*)catP16,
      colU, (float*)d_out);
}

// Round 22
// 700.358 us; speedup vs baseline: 1.0662x; 1.0662x over previous
//
#include <hip/hip_runtime.h>

// Problem constants (match reference setup_inputs)
#define D 64
constexpr int Pn  = 100000;
constexpr int Un  = 20000;
constexpr int Rn  = 1000;
constexpr int Cn  = 500;
constexpr int Tn  = 50;
constexpr int Bn  = 4096;
constexpr int ETn = 50000;
constexpr int NNZ_COL = 1000000;
constexpr int NNZ_REG = 300000;
constexpr int NNZ_CAT = 300000;
constexpr int NNZ_T   = 1000000;
constexpr int STILE = 7040;  // elements per scatter tile (55KB staging)
constexpr int NBMAX = 1024;  // max buckets per (graph,dir): reg dir1 = 1000
constexpr int CAP2 = 1536;   // poi-side bucket capacity (mean<=1279, sigma~36)
constexpr int NB2  = (Pn + 127) / 128;  // 782 poi buckets (shift 7)

static inline int cdiv(int a, int b) { return (a + b - 1) / b; }

typedef __attribute__((ext_vector_type(8))) short bf16x8;
typedef __attribute__((ext_vector_type(4))) float f32x4;

__device__ __forceinline__ unsigned short f2bf(float f) {
  unsigned u = __float_as_uint(f);
  unsigned r = (u + 0x7FFF + ((u >> 16) & 1)) >> 16;  // round-to-nearest-even
  return (unsigned short)r;
}
__device__ __forceinline__ float bflo(unsigned d) {
  return __uint_as_float(d << 16);
}
__device__ __forceinline__ float bfhi(unsigned d) {
  return __uint_as_float(d & 0xFFFF0000u);
}
__device__ __forceinline__ unsigned packbf(float a, float b) {
  return (unsigned)f2bf(a) | ((unsigned)f2bf(b) << 16);
}

// Per-graph sort descriptor (batched sort kernels select by blockIdx).
struct SG {
  const int* k1; const int* o1; const float* v1;
  const int* k2; const int* o2; const float* v2;
  int2* sd; int* rowptr; int* cursorB;
  int s1, nb1, nk1, cap1, nblk, nnz, tile0, bkt0;
};
struct SG4 { SG g[4]; };

// Fused-gate descriptor (4 gates over the same input; p16 only).
struct G4 {
  const float* W[4]; const float* b[4];
  unsigned short* P[4];
};

// Batched 64x64 weight-product descriptor (6 products).
struct W6 { const float* A[6]; const float* Bm[6]; float* O[6]; };

// ---------------------------------------------------------------------------
// gate4 via MFMA: o_g = x * sigmoid(x @ W_g + b_g), g=0..3; one read of X.
// Block = 4 waves; wave wv owns gate wv; 16-row X tile staged in LDS
// (padded stride 68 to break bank conflicts on fragment reads).
// Y tile = 2x mfma_f32_16x16x32_bf16 (K=64) per 16x16 col-tile.
// A frag: lane holds X[row0+(l&15)][kb*32+(l>>4)*8+j]; B frag: lane holds
// W[kb*32+(l>>4)*8+j][ct*16+(l&15)]; C/D: col=l&15, row=(l>>4)*4+reg (m89).
// Output staged in LDS, written as coalesced 2KB bf16 tiles.
// ---------------------------------------------------------------------------
__global__ __launch_bounds__(256) void gate4_kernel(G4 g,
                                                   const float* __restrict__ X,
                                                   int N) {
  __shared__ float sx[16][68];                 // padded X tile (f32)
  __shared__ unsigned short so[4][16][D];      // per-gate bf16 out tiles
  int tid = threadIdx.x, wv = tid >> 6, lane = tid & 63;
  int l15 = lane & 15, lq = lane >> 4;
  const float* Wg = g.W[wv];
  // B fragments (weights), loaded once: bfrag[kb][ct]
  bf16x8 bfrag[2][4];
#pragma unroll
  for (int kb = 0; kb < 2; ++kb)
#pragma unroll
    for (int ct = 0; ct < 4; ++ct)
#pragma unroll
      for (int j = 0; j < 8; ++j)
        bfrag[kb][ct][j] =
            (short)f2bf(Wg[(kb * 32 + lq * 8 + j) * D + ct * 16 + l15]);
  float blv[4];
#pragma unroll
  for (int ct = 0; ct < 4; ++ct) blv[ct] = g.b[wv][ct * 16 + l15];
  unsigned short* Pw = g.P[wv];
  for (int row0 = blockIdx.x * 16; row0 < N; row0 += gridDim.x * 16) {
    // stage 16x64 f32 tile (thread t -> row t/16, cols (t%16)*4..+3)
    {
      int r = tid >> 4, c4 = (tid & 15) * 4;
      *(float4*)&sx[r][c4] = *(const float4*)&X[(size_t)(row0 + r) * D + c4];
    }
    __syncthreads();
    // A fragments from LDS
    bf16x8 afrag[2];
#pragma unroll
    for (int kb = 0; kb < 2; ++kb) {
      const float* xr = &sx[l15][kb * 32 + lq * 8];
      float4 x0 = *(const float4*)&xr[0];
      float4 x1 = *(const float4*)&xr[4];
      afrag[kb][0] = (short)f2bf(x0.x); afrag[kb][1] = (short)f2bf(x0.y);
      afrag[kb][2] = (short)f2bf(x0.z); afrag[kb][3] = (short)f2bf(x0.w);
      afrag[kb][4] = (short)f2bf(x1.x); afrag[kb][5] = (short)f2bf(x1.y);
      afrag[kb][6] = (short)f2bf(x1.z); afrag[kb][7] = (short)f2bf(x1.w);
    }
#pragma unroll
    for (int ct = 0; ct < 4; ++ct) {
      f32x4 acc = {0.f, 0.f, 0.f, 0.f};
      acc = __builtin_amdgcn_mfma_f32_16x16x32_bf16(afrag[0], bfrag[0][ct],
                                                    acc, 0, 0, 0);
      acc = __builtin_amdgcn_mfma_f32_16x16x32_bf16(afrag[1], bfrag[1][ct],
                                                    acc, 0, 0, 0);
#pragma unroll
      for (int j = 0; j < 4; ++j) {
        int r = lq * 4 + j;
        float x = sx[r][ct * 16 + l15];
        float s = 1.f / (1.f + __expf(-(acc[j] + blv[ct])));
        so[wv][r][ct * 16 + l15] = f2bf(x * s);
      }
    }
    // coalesced out-copy of this wave's 16x64 bf16 tile (2KB)
    {
      const uint4* src = (const uint4*)&so[wv][0][0];
      uint4* dst = (uint4*)&Pw[(size_t)row0 * D];
      dst[lane] = src[lane];
      dst[lane + 64] = src[lane + 64];
    }
    __syncthreads();  // sx/so safe to overwrite next iter
  }
}

// Batched 64x64 weight products: O[p] = A[p] @ Bm[p]; 16 blocks/product.
__global__ __launch_bounds__(256) void wprod_kernel(W6 w) {
  __shared__ float sx[4][D];
  int tid = threadIdx.x, wv = tid >> 6, lane = tid & 63;
  int p = blockIdx.x >> 4, blk = blockIdx.x & 15;
  const float* A = w.A[p];
  const float* Bm = w.Bm[p];
  float* O = w.O[p];
  float wcol[D];
#pragma unroll
  for (int k = 0; k < D; ++k) wcol[k] = Bm[k * D + lane];
  int row = blk * 4 + wv;
  sx[wv][lane] = A[row * D + lane];
  float y = 0.f;
#pragma unroll
  for (int k = 0; k < D; ++k) y += sx[wv][k] * wcol[k];
  O[row * D + lane] = y;
}

// fused hetero edge update + residual (weights pre-folded):
// fused = msg' @ WpWf + e_buf @ WeWf ; fusedOut16 = bf16(fused);
// e_buf += fused ; accE += e_buf(new).
__global__ __launch_bounds__(256) void fused2_resid_kernel(
    const float* __restrict__ A, const float* __restrict__ W1,
    const float* __restrict__ W2, unsigned short* __restrict__ fusedOut16,
    float* __restrict__ e_buf, float* __restrict__ accE, int N) {
  __shared__ float sa[4][D], sb2[4][D];
  int tid = threadIdx.x, wv = tid >> 6, lane = tid & 63;
  float w1[D], w2[D];
#pragma unroll
  for (int k = 0; k < D; ++k) {
    w1[k] = W1[k * D + lane];
    w2[k] = W2[k * D + lane];
  }
  for (int row = blockIdx.x * 4 + wv; row < N; row += gridDim.x * 4) {
    sa[wv][lane]  = A[row * D + lane];
    float eo = e_buf[row * D + lane];
    sb2[wv][lane] = eo;
    float y = 0.f;
#pragma unroll
    for (int k = 0; k < D; ++k) y += sa[wv][k] * w1[k] + sb2[wv][k] * w2[k];
    fusedOut16[row * D + lane] = f2bf(y);
    float en = eo + y;
    e_buf[row * D + lane] = en;
    accE[row * D + lane] += en;
  }
}

// Batched cursor init: cursorB[local b] = fixed bucket base.
__global__ __launch_bounds__(256) void cursor_init_b_kernel(SG4 gs, int totb) {
  int b = blockIdx.x * blockDim.x + threadIdx.x;
  if (b >= totb) return;
  int gi = 3;
  while (gi > 0 && b < gs.g[gi].bkt0) --gi;
  const SG& g = gs.g[gi];
  int lb = b - g.bkt0;
  g.cursorB[lb] =
      (lb < g.nb1) ? lb * g.cap1 : g.nb1 * g.cap1 + (lb - g.nb1) * CAP2;
}

// ---------------------------------------------------------------------------
// Batched LDS-STAGED scatter: per (graph,dir,tile) block, bucket-sort the
// tile in LDS, then emit each bucket's run as a coalesced burst.
// LDS: stage 2*STILE ints | lbase NBMAX+1 | gbase NBMAX  (<= 64KB)
// ---------------------------------------------------------------------------
__global__ __launch_bounds__(1024) void scatter_b_kernel(SG4 gs) {
  extern __shared__ int ls[];
  int2* stage = (int2*)ls;             // STILE int2 = 55KB
  int* lcnt   = ls;                    // aliases stage (first nb ints)
  int* lbase  = ls + 2 * STILE;        // NBMAX+1
  int* gbase  = lbase + (NBMAX + 1);   // NBMAX
  __shared__ int wsum[17];
  int b = blockIdx.x;
  int gi = 3;
  while (gi > 0 && b < gs.g[gi].tile0) --gi;
  const SG& g = gs.g[gi];
  int t = b - g.tile0;
  bool d2 = t >= g.nblk;
  const int* kk = d2 ? g.k2 : g.k1;
  const int* oo = d2 ? g.o2 : g.o1;
  const float* vv = d2 ? g.v2 : g.v1;
  int sft = d2 ? 7 : g.s1;
  int kb = d2 ? g.nb1 : 0;
  int nb = d2 ? NB2 : g.nb1;
  int msk = (1 << sft) - 1;
  int tile = d2 ? t - g.nblk : t;
  int tid = threadIdx.x;
  for (int k = tid; k < nb; k += 1024) lcnt[k] = 0;
  __syncthreads();
  int t0 = tile * STILE, t1 = min(t0 + STILE, g.nnz);
  int fill = t1 - t0;
  int key[7], off[7], ox[7], vx[7];
#pragma unroll
  for (int j = 0; j < 7; ++j) {
    int i = t0 + j * 1024 + tid;
    if (i < t1) {
      int r = kk[i];
      key[j] = r >> sft;
      ox[j] = ((r & msk) << 17) | oo[i];
      vx[j] = __float_as_int(vv[i]);
      off[j] = atomicAdd(&lcnt[key[j]], 1);
    } else {
      key[j] = -1; off[j] = 0; ox[j] = 0; vx[j] = 0;
    }
  }
  __syncthreads();
  // exclusive scan of lcnt[0..nb) -> lbase; reserve global space -> gbase
  {
    int lane = tid & 63, wv = tid >> 6;
    int c = (tid < nb) ? lcnt[tid] : 0;
    int sc = c;
#pragma unroll
    for (int d = 1; d < 64; d <<= 1) {
      int y = __shfl_up(sc, d);
      if (lane >= d) sc += y;
    }
    if (lane == 63) wsum[wv] = sc;
    __syncthreads();
    if (tid < 16) {
      int w = wsum[tid];
#pragma unroll
      for (int d = 1; d < 16; d <<= 1) {
        int y = __shfl_up(w, d);
        if (lane >= d) w += y;
      }
      wsum[tid] = w;
    }
    __syncthreads();
    int woff = (wv == 0) ? 0 : wsum[wv - 1];
    if (tid < nb) {
      lbase[tid] = woff + sc - c;
      gbase[tid] = c ? atomicAdd(&g.cursorB[kb + tid], c) : 0;
    }
    if (tid == 0) lbase[nb] = fill;
  }
  __syncthreads();  // lcnt dead; staging (aliased) may now be written
#pragma unroll
  for (int j = 0; j < 7; ++j)
    if (key[j] >= 0) stage[lbase[key[j]] + off[j]] = make_int2(ox[j], vx[j]);
  __syncthreads();
  // out-copy: consecutive i -> consecutive dst within runs (coalesced)
  for (int i = tid; i < fill; i += 1024) {
    int lo = 0, hi = nb;
    while (hi - lo > 1) {
      int mid = (lo + hi) >> 1;
      if (lbase[mid] <= i) lo = mid; else hi = mid;
    }
    g.sd[gbase[lo] + (i - lbase[lo])] = stage[i];
  }
}

// Batched refine: bucket-grouped -> exact row-grouped IN PLACE + exact
// rowptr. Block per bucket; <=2048 elems staged in registers. rows==1:
// just write rowptr.
__global__ __launch_bounds__(256) void refine_b_kernel(SG4 gs) {
  __shared__ int cnt[128];
  __shared__ int wsum[2];
  int bg = blockIdx.x;
  int gi = 3;
  while (gi > 0 && bg < gs.g[gi].bkt0) --gi;
  const SG& g = gs.g[gi];
  int b = bg - g.bkt0;
  int tid = threadIdx.x;
  int sft, row0, kbase, klim, bstart;
  if (b < g.nb1) {
    sft = g.s1; row0 = b << g.s1; kbase = 0; klim = g.nk1;
    bstart = b * g.cap1;
  } else {
    sft = 7; row0 = (b - g.nb1) << 7; kbase = g.nk1; klim = Pn;
    bstart = g.nb1 * g.cap1 + (b - g.nb1) * CAP2;
  }
  int rows = min(1 << sft, klim - row0);
  int bend = g.cursorB[b];
  if (rows == 1) {
    if (tid == 0) g.rowptr[kbase + row0] = bstart;
    return;
  }
  if (tid < rows) cnt[tid] = 0;
  __syncthreads();
  int2 st[8];
#pragma unroll
  for (int j = 0; j < 8; ++j) {
    int i = bstart + tid + (j << 8);
    st[j] = (i < bend) ? g.sd[i] : make_int2(0, 0);
  }
#pragma unroll
  for (int j = 0; j < 8; ++j) {
    int i = bstart + tid + (j << 8);
    if (i < bend) atomicAdd(&cnt[st[j].x >> 17], 1);
  }
  __syncthreads();
  int v = 0, sc = 0;
  if (tid < 128) {
    v = (tid < rows) ? cnt[tid] : 0;
    sc = v;
    int lane = tid & 63;
#pragma unroll
    for (int d = 1; d < 64; d <<= 1) {
      int y = __shfl_up(sc, d);
      if (lane >= d) sc += y;
    }
    if (lane == 63) wsum[tid >> 6] = sc;
  }
  __syncthreads();
  int excl = sc - v + ((tid >= 64 && tid < 128) ? wsum[0] : 0);
  __syncthreads();  // cnt reads done before overwrite
  if (tid < rows) {
    g.rowptr[kbase + row0 + tid] = bstart + excl;
    cnt[tid] = excl;  // becomes placement cursor
  }
  __syncthreads();
#pragma unroll
  for (int j = 0; j < 8; ++j) {
    int i = bstart + tid + (j << 8);
    if (i < bend) {
      int r = st[j].x >> 17;
      int dst = bstart + atomicAdd(&cnt[r], 1);
      g.sd[dst] = st[j];
    }
  }
}

// ---------------------------------------------------------------------------
// Exact-CSR SpMM: wave per row, 8 nnz per gather instruction (8 lanes x
// uint4 = 128B bf16 row per nnz). Row end = min(rowptr[idx+1], bucket end).
// Merge via shfl ^8,^16,^32; lanes 0-7 do the epilogue. Modes: Yf (f32 out),
// Y128 (bf16 out), or C-mode bf16 p RMW (p128 += y) with acc modes:
// amode 1: a128 = p_old + p_new (pure store; layer-1 acc init+update),
// amode 2: a128 += p_new (layer-2 acc update).
// ---------------------------------------------------------------------------
__global__ __launch_bounds__(256) void spmm_csr_kernel(
    const int* __restrict__ rowptr, const int* __restrict__ bEnd, int base,
    int nkx, int sft, int boff, const int2* __restrict__ sd,
    const uint4* __restrict__ X128, float* __restrict__ Yf,
    uint4* __restrict__ Y128, uint4* __restrict__ p128,
    uint4* __restrict__ a128, int amode, int nrows) {
  int lane = threadIdx.x & 63;
  int q = lane >> 3, l3 = lane & 7;  // octet q (0..7), lane-in-octet
  int w = (int)((blockIdx.x * (long)blockDim.x + threadIdx.x) >> 6);
  if (w >= nrows) return;
  int idx = base + w;
  int start = rowptr[idx];
  int be = bEnd[boff + (w >> sft)];
  int end = (idx + 1 < nkx) ? min(rowptr[idx + 1], be) : be;
  float a0 = 0.f, a1 = 0.f, a2 = 0.f, a3 = 0.f;
  float a4 = 0.f, a5 = 0.f, a6 = 0.f, a7 = 0.f;
  float b0 = 0.f, b1 = 0.f, b2 = 0.f, b3 = 0.f;
  float b4 = 0.f, b5 = 0.f, b6 = 0.f, b7 = 0.f;
  int n = start + q;  // this octet's nnz stream (stride 8)
  for (; n + 8 < end; n += 16) {
    int2 c0 = sd[n], c1 = sd[n + 8];
    uint4 d0 = X128[(size_t)(c0.x & 0x1FFFF) * 8 + l3];
    uint4 d1 = X128[(size_t)(c1.x & 0x1FFFF) * 8 + l3];
    float v0 = __int_as_float(c0.y), v1 = __int_as_float(c1.y);
    a0 += v0 * bflo(d0.x); a1 += v0 * bfhi(d0.x);
    a2 += v0 * bflo(d0.y); a3 += v0 * bfhi(d0.y);
    a4 += v0 * bflo(d0.z); a5 += v0 * bfhi(d0.z);
    a6 += v0 * bflo(d0.w); a7 += v0 * bfhi(d0.w);
    b0 += v1 * bflo(d1.x); b1 += v1 * bfhi(d1.x);
    b2 += v1 * bflo(d1.y); b3 += v1 * bfhi(d1.y);
    b4 += v1 * bflo(d1.z); b5 += v1 * bfhi(d1.z);
    b6 += v1 * bflo(d1.w); b7 += v1 * bfhi(d1.w);
  }
  for (; n < end; n += 8) {
    int2 cv = sd[n];
    uint4 dv = X128[(size_t)(cv.x & 0x1FFFF) * 8 + l3];
    float v = __int_as_float(cv.y);
    a0 += v * bflo(dv.x); a1 += v * bfhi(dv.x);
    a2 += v * bflo(dv.y); a3 += v * bfhi(dv.y);
    a4 += v * bflo(dv.z); a5 += v * bfhi(dv.z);
    a6 += v * bflo(dv.w); a7 += v * bfhi(dv.w);
  }
  float y0 = a0 + b0, y1 = a1 + b1, y2 = a2 + b2, y3 = a3 + b3;
  float y4 = a4 + b4, y5 = a5 + b5, y6 = a6 + b6, y7 = a7 + b7;
#pragma unroll
  for (int m = 8; m <= 32; m <<= 1) {
    y0 += __shfl(y0, lane ^ m); y1 += __shfl(y1, lane ^ m);
    y2 += __shfl(y2, lane ^ m); y3 += __shfl(y3, lane ^ m);
    y4 += __shfl(y4, lane ^ m); y5 += __shfl(y5, lane ^ m);
    y6 += __shfl(y6, lane ^ m); y7 += __shfl(y7, lane ^ m);
  }
  if (lane >= 8) return;
  size_t o = (size_t)w * 8 + l3;  // uint4 index (8 bf16 elems)
  if (p128) {
    uint4 pv = p128[o];
    float q0 = bflo(pv.x), q1 = bfhi(pv.x);
    float q2 = bflo(pv.y), q3 = bfhi(pv.y);
    float q4 = bflo(pv.z), q5 = bfhi(pv.z);
    float q6 = bflo(pv.w), q7 = bfhi(pv.w);
    float p0 = q0 + y0, p1 = q1 + y1, p2 = q2 + y2, p3 = q3 + y3;
    float p4 = q4 + y4, p5 = q5 + y5, p6 = q6 + y6, p7 = q7 + y7;
    uint4 pn;
    pn.x = packbf(p0, p1); pn.y = packbf(p2, p3);
    pn.z = packbf(p4, p5); pn.w = packbf(p6, p7);
    p128[o] = pn;
    if (amode == 1) {  // acc = p_old + p_new (pure store)
      uint4 an;
      an.x = packbf(q0 + p0, q1 + p1);
      an.y = packbf(q2 + p2, q3 + p3);
      an.z = packbf(q4 + p4, q5 + p5);
      an.w = packbf(q6 + p6, q7 + p7);
      a128[o] = an;
    } else if (amode == 2) {  // acc += p_new
      uint4 av = a128[o];
      uint4 an;
      an.x = packbf(bflo(av.x) + p0, bfhi(av.x) + p1);
      an.y = packbf(bflo(av.y) + p2, bfhi(av.y) + p3);
      an.z = packbf(bflo(av.z) + p4, bfhi(av.z) + p5);
      an.w = packbf(bflo(av.w) + p6, bfhi(av.w) + p7);
      a128[o] = an;
    }
  } else if (Y128) {
    uint4 pk;
    pk.x = packbf(y0, y1); pk.y = packbf(y2, y3);
    pk.z = packbf(y4, y5); pk.w = packbf(y6, y7);
    Y128[o] = pk;
  } else {
    float4 lo; lo.x = y0; lo.y = y1; lo.z = y2; lo.w = y3;
    float4 hi; hi.x = y4; hi.y = y5; hi.z = y6; hi.w = y7;
    *(float4*)&Yf[(size_t)w * D + 8 * l3] = lo;
    *(float4*)&Yf[(size_t)w * D + 8 * l3 + 4] = hi;
  }
}

// a = src; b = src  (float4)
__global__ __launch_bounds__(256) void copy2_kernel(
    const float4* __restrict__ s, float4* __restrict__ a,
    float4* __restrict__ b, int n4) {
  int i = blockIdx.x * blockDim.x + threadIdx.x;
  if (i < n4) {
    float4 v = s[i];
    a[i] = v;
    b[i] = v;
  }
}

// ---------------------------------------------------------------------------
// Final pooling over bf16 acc tables: wave per user, quarter q handles
// timesteps t=q,q+4,...; 16 lanes x uint2 = 128B row per gather. Merge via
// shfl ^16,^32; lanes 0-15 write float4 outputs. colU stays f32.
// ---------------------------------------------------------------------------
__global__ __launch_bounds__(256) void final_kernel(
    const int* __restrict__ user_idx, const int* __restrict__ seq,
    const int* __restrict__ mask, const uint2* __restrict__ colP16,
    const uint2* __restrict__ transP16, const uint2* __restrict__ regP16,
    const uint2* __restrict__ catP16, const float* __restrict__ colU,
    float* __restrict__ out) {
  int lane = threadIdx.x & 63;
  int q = lane >> 4, l4 = lane & 15;
  int wid = (int)((blockIdx.x * (long)blockDim.x + threadIdx.x) >> 6);
  if (wid >= Bn) return;
  float c0 = 0.f, c1 = 0.f, c2 = 0.f, c3 = 0.f;
  float t0 = 0.f, t1 = 0.f, t2 = 0.f, t3 = 0.f;
  float r0 = 0.f, r1 = 0.f, r2 = 0.f, r3 = 0.f;
  float g0 = 0.f, g1 = 0.f, g2 = 0.f, g3 = 0.f;
  int cnt = 0;
  for (int t = q; t < Tn; t += 4) {
    int m = mask[wid * Tn + t];
    int idx = seq[wid * Tn + t];
    cnt += m;
    if (m && idx < Pn) {
      size_t ro = (size_t)idx * 16 + l4;
      uint2 dc = colP16[ro];
      uint2 dt = transP16[ro];
      uint2 dr = regP16[ro];
      uint2 dg = catP16[ro];
      c0 += bflo(dc.x); c1 += bfhi(dc.x); c2 += bflo(dc.y); c3 += bfhi(dc.y);
      t0 += bflo(dt.x); t1 += bfhi(dt.x); t2 += bflo(dt.y); t3 += bfhi(dt.y);
      r0 += bflo(dr.x); r1 += bfhi(dr.x); r2 += bflo(dr.y); r3 += bfhi(dr.y);
      g0 += bflo(dg.x); g1 += bfhi(dg.x); g2 += bflo(dg.y); g3 += bfhi(dg.y);
    }
  }
  cnt += __shfl(cnt, lane ^ 16); cnt += __shfl(cnt, lane ^ 32);
  c0 += __shfl(c0, lane ^ 16); c0 += __shfl(c0, lane ^ 32);
  c1 += __shfl(c1, lane ^ 16); c1 += __shfl(c1, lane ^ 32);
  c2 += __shfl(c2, lane ^ 16); c2 += __shfl(c2, lane ^ 32);
  c3 += __shfl(c3, lane ^ 16); c3 += __shfl(c3, lane ^ 32);
  t0 += __shfl(t0, lane ^ 16); t0 += __shfl(t0, lane ^ 32);
  t1 += __shfl(t1, lane ^ 16); t1 += __shfl(t1, lane ^ 32);
  t2 += __shfl(t2, lane ^ 16); t2 += __shfl(t2, lane ^ 32);
  t3 += __shfl(t3, lane ^ 16); t3 += __shfl(t3, lane ^ 32);
  r0 += __shfl(r0, lane ^ 16); r0 += __shfl(r0, lane ^ 32);
  r1 += __shfl(r1, lane ^ 16); r1 += __shfl(r1, lane ^ 32);
  r2 += __shfl(r2, lane ^ 16); r2 += __shfl(r2, lane ^ 32);
  r3 += __shfl(r3, lane ^ 16); r3 += __shfl(r3, lane ^ 32);
  g0 += __shfl(g0, lane ^ 16); g0 += __shfl(g0, lane ^ 32);
  g1 += __shfl(g1, lane ^ 16); g1 += __shfl(g1, lane ^ 32);
  g2 += __shfl(g2, lane ^ 16); g2 += __shfl(g2, lane ^ 32);
  g3 += __shfl(g3, lane ^ 16); g3 += __shfl(g3, lane ^ 32);
  if (lane >= 16) return;
  float dn = 1.f / (float)(cnt > 0 ? cnt : 1);
  const float inv = 1.f / 3.f;  // 1/(N_LAYERS+1), common to all four nets
  int u = user_idx[wid];
  float4 cu = *(const float4*)&colU[(size_t)u * D + 4 * l4];
  size_t ob = (size_t)wid * D + 4 * l4;
  float4 o0;
  o0.x = (cu.x + c0 * dn) * inv; o0.y = (cu.y + c1 * dn) * inv;
  o0.z = (cu.z + c2 * dn) * inv; o0.w = (cu.w + c3 * dn) * inv;
  *(float4*)&out[0 * Bn * D + ob] = o0;
  float4 o1v;
  o1v.x = t0 * dn * inv; o1v.y = t1 * dn * inv;
  o1v.z = t2 * dn * inv; o1v.w = t3 * dn * inv;
  *(float4*)&out[1 * Bn * D + ob] = o1v;
  float4 o2v;
  o2v.x = r0 * dn * inv; o2v.y = r1 * dn * inv;
  o2v.z = r2 * dn * inv; o2v.w = r3 * dn * inv;
  *(float4*)&out[2 * Bn * D + ob] = o2v;
  float4 o3v;
  o3v.x = g0 * dn * inv; o3v.y = g1 * dn * inv;
  o3v.z = g2 * dn * inv; o3v.w = g3 * dn * inv;
  *(float4*)&out[3 * Bn * D + ob] = o3v;
}

extern "C" void kernel_launch(void* const* d_in, const int* in_sizes, int n_in,
                              void* d_out, int out_size, void* d_ws,
                              size_t ws_size, hipStream_t stream) {
  (void)in_sizes; (void)n_in; (void)out_size; (void)ws_size;
  const int*   user_idx      = (const int*)d_in[0];
  const int*   user_seq      = (const int*)d_in[1];
  const int*   user_seq_mask = (const int*)d_in[2];
  const int*   col_poi_idx   = (const int*)d_in[3];
  const int*   col_user_idx  = (const int*)d_in[4];
  const float* col_vals_pe   = (const float*)d_in[5];
  const float* col_vals_ep   = (const float*)d_in[6];
  const int*   reg_poi_idx   = (const int*)d_in[7];
  const int*   reg_region_idx= (const int*)d_in[8];
  const float* reg_vals_pe   = (const float*)d_in[9];
  const float* reg_vals_ep   = (const float*)d_in[10];
  const int*   cat_poi_idx   = (const int*)d_in[11];
  const int*   cat_cat_idx   = (const int*)d_in[12];
  const float* cat_vals_pe   = (const float*)d_in[13];
  const float* cat_vals_ep   = (const float*)d_in[14];
  const int*   trans_poi_idx = (const int*)d_in[15];
  const int*   trans_edge_idx= (const int*)d_in[16];
  const float* trans_vals_tar= (const float*)d_in[17];
  const float* trans_vals_src= (const float*)d_in[18];
  const float* poi_emb       = (const float*)d_in[19];
  const float* user_emb      = (const float*)d_in[20];
  const float* region_emb    = (const float*)d_in[21];
  const float* cat_emb       = (const float*)d_in[22];
  const float* w_gate_col    = (const float*)d_in[23];
  const float* b_gate_col    = (const float*)d_in[24];
  const float* w_gate_trans  = (const float*)d_in[25];
  const float* b_gate_trans  = (const float*)d_in[26];
  const float* w_gate_reg    = (const float*)d_in[27];
  const float* b_gate_reg    = (const float*)d_in[28];
  const float* w_gate_cat    = (const float*)d_in[29];
  const float* b_gate_cat    = (const float*)d_in[30];
  const float* col_Wp = (const float*)d_in[31];
  const float* col_We = (const float*)d_in[32];
  const float* col_Wf = (const float*)d_in[33];
  const float* reg_Wp = (const float*)d_in[34];
  const float* reg_We = (const float*)d_in[35];
  const float* reg_Wf = (const float*)d_in[36];
  const float* cat_Wp = (const float*)d_in[37];
  const float* cat_We = (const float*)d_in[38];
  const float* cat_Wf = (const float*)d_in[39];

  float* ws = (float*)d_ws;
  size_t off = 0;
  auto alloc = [&](size_t n) { float* p = ws + off; off += n; return p; };
  const size_t PD = (size_t)Pn * D;
  const size_t UD = (size_t)Un * D;
  const size_t ED = (size_t)ETn * D;

  float* colU   = alloc(UD);
  float* e_buf  = alloc(UD);
  float* tmpE1  = alloc(UD);
  float* acce   = alloc((size_t)Rn * D);
  float* Wbuf   = alloc(6 * D * D);  // WpWf/WeWf for the 3 hetero nets
  unsigned short* tmpE2_16 = (unsigned short*)alloc(UD / 2);
  unsigned short* tmpE1_16 = (unsigned short*)alloc(ED / 2);
  unsigned short* p16_0    = (unsigned short*)alloc(PD / 2);  // per-net p
  unsigned short* p16_1    = (unsigned short*)alloc(PD / 2);
  unsigned short* p16_2    = (unsigned short*)alloc(PD / 2);
  unsigned short* p16_3    = (unsigned short*)alloc(PD / 2);
  unsigned short* colP16   = (unsigned short*)alloc(PD / 2);  // bf16 acc tables
  unsigned short* regP16   = (unsigned short*)alloc(PD / 2);
  unsigned short* catP16   = (unsigned short*)alloc(PD / 2);
  unsigned short* transP16 = (unsigned short*)alloc(PD / 2);

  // Per-graph geometry (col, reg, cat, trans)
  const int s1_[4]   = {5, 0, 0, 6};
  const int nk1_[4]  = {Un, Rn, Cn, ETn};
  const int cap1_[4] = {2048, 512, 1024, 1536};
  const int nnz_[4]  = {NNZ_COL, NNZ_REG, NNZ_CAT, NNZ_T};
  SG4 gs;
  int tile0 = 0, bkt0 = 0;
  size_t sdoff = 0, rpoff = 0;
  int2* sdbase;
  int *rpbase, *curbase;
  {
    size_t sdtot = 0;
    for (int i = 0; i < 4; ++i) {
      int nb1 = cdiv(nk1_[i], 1 << s1_[i]);
      sdtot += (size_t)nb1 * cap1_[i] + (size_t)NB2 * CAP2;
    }
    sdbase = (int2*)alloc(2 * sdtot);
    rpbase = (int*)alloc(Un + Rn + Cn + ETn + 4 * Pn + 8);
    curbase = (int*)alloc(4 * 2048);
  }
  const int* k1s[4] = {col_user_idx, reg_region_idx, cat_cat_idx,
                       trans_edge_idx};
  const int* o1s[4] = {col_poi_idx, reg_poi_idx, cat_poi_idx, trans_poi_idx};
  const float* v1s[4] = {col_vals_pe, reg_vals_pe, cat_vals_pe,
                         trans_vals_tar};
  const float* v2s[4] = {col_vals_ep, reg_vals_ep, cat_vals_ep,
                         trans_vals_src};
  for (int i = 0; i < 4; ++i) {
    SG& g = gs.g[i];
    g.k1 = k1s[i]; g.o1 = o1s[i]; g.v1 = v1s[i];
    g.k2 = o1s[i]; g.o2 = k1s[i]; g.v2 = v2s[i];
    g.s1 = s1_[i]; g.nk1 = nk1_[i]; g.cap1 = cap1_[i]; g.nnz = nnz_[i];
    g.nb1 = cdiv(g.nk1, 1 << g.s1);
    g.nblk = cdiv(g.nnz, STILE);
    g.sd = sdbase + sdoff;
    g.rowptr = rpbase + rpoff;
    g.cursorB = curbase + i * 2048;
    g.tile0 = tile0; g.bkt0 = bkt0;
    sdoff += (size_t)g.nb1 * g.cap1 + (size_t)NB2 * CAP2;
    rpoff += g.nk1 + Pn;
    tile0 += 2 * g.nblk;
    bkt0 += g.nb1 + NB2;
  }
  int tottiles = tile0, totbkt = bkt0;

  // --- precompute all 6 weight products in one launch ---
  W6 w6;
  w6.A[0] = col_Wp; w6.Bm[0] = col_Wf;          w6.O[0] = Wbuf + 0 * D * D;
  w6.A[1] = col_We; w6.Bm[1] = col_Wf + D * D;  w6.O[1] = Wbuf + 1 * D * D;
  w6.A[2] = reg_Wp; w6.Bm[2] = reg_Wf;          w6.O[2] = Wbuf + 2 * D * D;
  w6.A[3] = reg_We; w6.Bm[3] = reg_Wf + D * D;  w6.O[3] = Wbuf + 3 * D * D;
  w6.A[4] = cat_Wp; w6.Bm[4] = cat_Wf;          w6.O[4] = Wbuf + 4 * D * D;
  w6.A[5] = cat_We; w6.Bm[5] = cat_Wf + D * D;  w6.O[5] = Wbuf + 5 * D * D;
  wprod_kernel<<<96, 256, 0, stream>>>(w6);

  // --- fused 4-gate MFMA pass (reads poi_emb once; p16 only) ---
  G4 g4;
  g4.W[0] = w_gate_col;   g4.b[0] = b_gate_col;   g4.P[0] = p16_0;
  g4.W[1] = w_gate_reg;   g4.b[1] = b_gate_reg;   g4.P[1] = p16_1;
  g4.W[2] = w_gate_cat;   g4.b[2] = b_gate_cat;   g4.P[2] = p16_2;
  g4.W[3] = w_gate_trans; g4.b[3] = b_gate_trans; g4.P[3] = p16_3;
  gate4_kernel<<<2048, 256, 0, stream>>>(g4, poi_emb, Pn);

  // --- batched sort phase (all four graphs) ---
  cursor_init_b_kernel<<<cdiv(totbkt, 256), 256, 0, stream>>>(gs, totbkt);
  scatter_b_kernel<<<tottiles, 1024, (2 * STILE + 2 * NBMAX + 1) * 4,
                     stream>>>(gs);
  refine_b_kernel<<<totbkt, 256, 0, stream>>>(gs);

  const int GCAP = 1024;

  auto spmm = [&](const SG& g, int base, int sft, int boff,
                  const unsigned short* X16, float* Yf, unsigned short* Y16,
                  unsigned short* prmw, unsigned short* armw, int amode,
                  int nrows) {
    spmm_csr_kernel<<<cdiv(nrows, 4), 256, 0, stream>>>(
        g.rowptr, g.cursorB, base, g.nk1 + Pn, sft, boff, g.sd,
        (const uint4*)X16, Yf, (uint4*)Y16, (uint4*)prmw, (uint4*)armw, amode,
        nrows);
  };

  auto hetero = [&](int gi, const float* edge_emb, int Ne, float* accE,
                    unsigned short* p16, unsigned short* acc16) {
    const SG& g = gs.g[gi];
    const float* WpWf = Wbuf + (2 * gi) * D * D;
    const float* WeWf = Wbuf + (2 * gi + 1) * D * D;
    copy2_kernel<<<cdiv(Ne * D / 4, 256), 256, 0, stream>>>(
        (const float4*)edge_emb, (float4*)e_buf, (float4*)accE, Ne * D / 4);
    for (int l = 0; l < 2; ++l) {
      // poi_msg' = A_pe @ p16  (Wp folded into WpWf downstream)
      spmm(g, 0, g.s1, 0, p16, tmpE1, nullptr, nullptr, nullptr, 0, Ne);
      fused2_resid_kernel<<<min(cdiv(Ne, 4), GCAP), 256, 0, stream>>>(
          tmpE1, WpWf, WeWf, tmpE2_16, e_buf, accE, Ne);
      // prop + bf16 p RMW; layer 1 stores acc = p_old + p_new (init+update),
      // layer 2 does acc += p_new.
      spmm(g, g.nk1, 7, g.nb1, tmpE2_16, nullptr, nullptr, p16, acc16,
           (l == 0) ? 1 : 2, Pn);
    }
  };

  hetero(0, user_emb, Un, colU, p16_0, colP16);
  hetero(1, region_emb, Rn, acce, p16_1, regP16);
  hetero(2, cat_emb, Cn, acce, p16_2, catP16);

  // --- directed trans net ---
  {
    const SG& g = gs.g[3];
    for (int l = 0; l < 2; ++l) {
      spmm(g, 0, g.s1, 0, p16_3, nullptr, tmpE1_16, nullptr, nullptr, 0, ETn);
      spmm(g, g.nk1, 7, g.nb1, tmpE1_16, nullptr, nullptr, p16_3, transP16,
           (l == 0) ? 1 : 2, Pn);
    }
  }

  // --- sequence pooling + output (bf16 acc tables) ---
  final_kernel<<<cdiv(Bn * 64, 256), 256, 0, stream>>>(
      user_idx, user_seq, user_seq_mask, (const uint2*)colP16,
      (const uint2*)transP16, (const uint2*)regP16, (const uint2*)catP16,
      colU, (float*)d_out);
}